// Round 3
// baseline (148.535 us; speedup 1.0000x reference)
//
#include <hip/hip_runtime.h>
#include <math.h>

// ---------------------------------------------------------------------------
// v4 — non-temporal stores.
//
// Theory: v2 (compute cut) and v3 (contiguous write windows) were both null;
// the kernel window is pinned at ~60 us ~= (our 134 MB + leftover dirty
// poison-fill drain) / 6.6 TB/s. Our regular stores allocate in TCC and
// churn the 512 MB of poison-dirty lines. Fix: __builtin_nontemporal_store
// (global_store_dwordx4 nt) — bypass cache allocation, stream to HBM.
// Output is write-once/never-read: the textbook NT case.
//
// Structure otherwise v3: each block owns PAB_ROWS=8 full-width rows = one
// contiguous 128 KB window swept in ascending address order.
//
//   Phase 1 — per-block redundant batch moments in f64 (order-identical
//   across versions -> bit-identical threshold):
//     sum_d  = 2N(S2x+S2y) - 2(S1x^2 + S1y^2)
//     sum_d2 = [2N S4x - 8 S3x S1x + 6 S2x^2] + [same for y]
//            + 2*[2N A22 - 4 A21 S1y - 4 A12 S1x + 2 S2x S2y + 4 A11^2]
//
//   forward_bias via 0.5 + 0.5*dx*rsqrt(d2) == 0.5*(1+cos(atan2(dy,dx)));
//   exactly 1.0 at the zero pair, matching atan2(0,1)=0.
// ---------------------------------------------------------------------------
#define PAB_ROWS 8
#define PAB_TPB  256   // threads per block; one column pass = PAB_TPB*4 cols

typedef __attribute__((ext_vector_type(4))) float f32x4;

__device__ __forceinline__ void pab_store_nt(float* p, float4 v) {
    f32x4 w = {v.x, v.y, v.z, v.w};
    __builtin_nontemporal_store(w, (f32x4*)p);
}

// ---- Phase 1: batch moments -> threshold (all threads must call; contains
// barriers). Reduction order identical to v1/v2/v3 -> bit-identical thr.
__device__ __forceinline__ float pab_threshold(const float2* __restrict__ emb,
                                               int S, int tid) {
    double s[12];
#pragma unroll
    for (int k = 0; k < 12; ++k) s[k] = 0.0;

    for (int idx0 = tid * 4; idx0 < S; idx0 += PAB_TPB * 4) {
        float4 c0 = *(const float4*)(emb + idx0);      // p0, p1
        float4 c1 = *(const float4*)(emb + idx0 + 2);  // p2, p3
        float xs[4] = {c0.x, c0.z, c1.x, c1.z};
        float ys[4] = {c0.y, c0.w, c1.y, c1.w};
#pragma unroll
        for (int k = 0; k < 4; ++k) {
            if (idx0 + k >= S) break;
            double x = (double)xs[k], y = (double)ys[k];
            double x2 = x * x, y2 = y * y;
            s[0]  += x;        s[1]  += y;
            s[2]  += x2;       s[3]  += y2;
            s[4]  += x2 * x;   s[5]  += y2 * y;
            s[6]  += x2 * x2;  s[7]  += y2 * y2;
            s[8]  += x * y;    s[9]  += x2 * y;
            s[10] += x * y2;   s[11] += x2 * y2;
        }
    }

    // Wave (64-lane) shuffle reduction — no barriers.
#pragma unroll
    for (int off = 32; off > 0; off >>= 1) {
#pragma unroll
        for (int k = 0; k < 12; ++k)
            s[k] += __shfl_down(s[k], off, 64);
    }

    __shared__ double part[PAB_TPB / 64][12];
    __shared__ double tot[12];
    __shared__ float thr_sh;
    const int wave = tid >> 6, lane = tid & 63;
    if (lane == 0) {
#pragma unroll
        for (int k = 0; k < 12; ++k) part[wave][k] = s[k];
    }
    __syncthreads();
    if (tid < 12) {
        double t = 0.0;
#pragma unroll
        for (int w = 0; w < PAB_TPB / 64; ++w) t += part[w][tid];
        tot[tid] = t;
    }
    __syncthreads();
    if (tid == 0) {
        double N = (double)S;
        double M = N * N;
        double S1x = tot[0], S1y = tot[1], S2x = tot[2], S2y = tot[3];
        double S3x = tot[4], S3y = tot[5], S4x = tot[6], S4y = tot[7];
        double A11 = tot[8], A21 = tot[9], A12 = tot[10], A22 = tot[11];

        double sum_d = 2.0 * N * (S2x + S2y) - 2.0 * (S1x * S1x + S1y * S1y);
        double qx = 2.0 * N * S4x - 8.0 * S3x * S1x + 6.0 * S2x * S2x;
        double qy = 2.0 * N * S4y - 8.0 * S3y * S1y + 6.0 * S2y * S2y;
        double cross = 2.0 * N * A22 - 4.0 * A21 * S1y - 4.0 * A12 * S1x
                     + 2.0 * S2x * S2y + 4.0 * A11 * A11;
        double sum_d2 = qx + qy + 2.0 * cross;

        double mean = sum_d / M;
        double var  = (sum_d2 - sum_d * sum_d / M) / (M - 1.0);  // ddof=1
        thr_sh = (float)(mean + 1.25 * sqrt(var));
    }
    __syncthreads();
    return thr_sh;
}

__device__ __forceinline__ float4 pab_compute4(float2 pi, const float* xs,
        const float* ys, float thr, int i, int j0) {
    float4 res;
    float* rp = &res.x;
#pragma unroll
    for (int k = 0; k < 4; ++k) {
        float dx = pi.x - xs[k];
        float dy = pi.y - ys[k];
        float d2 = fmaf(dx, dx, dy * dy);
        float bias = (d2 > 0.0f) ? fmaf(0.5f * dx, rsqrtf(d2), 0.5f) : 1.0f;
        bool valid = (d2 <= thr) & ((j0 + k) <= i);
        rp[k] = valid ? bias : 0.0f;
    }
    return res;
}

// ---- Primary kernel: 8 full-width rows per block, linear NT store stream.
template<int NPASS>
__global__ __launch_bounds__(PAB_TPB) void pab_rows_kernel(
        const float* __restrict__ r, float* __restrict__ out, int S) {
    const int b = blockIdx.y;
    const float2* emb = (const float2*)r + (size_t)b * S;
    const int tid = threadIdx.x;
    const int i0  = blockIdx.x * PAB_ROWS;

    const float thr = pab_threshold(emb, S, tid);

    // Hoist the 8 block-uniform row points.
    float2 pis[PAB_ROWS];
#pragma unroll
    for (int rr = 0; rr < PAB_ROWS; ++rr)
        pis[rr] = emb[min(i0 + rr, S - 1)];

    // Hoist this thread's column points for ALL passes (static indices ->
    // registers: NPASS<=4 -> 32 VGPRs). Same columns reused by every row.
    float xs[NPASS][4], ys[NPASS][4];
#pragma unroll
    for (int p = 0; p < NPASS; ++p) {
        const int j0 = p * (PAB_TPB * 4) + tid * 4;
        float4 c0 = *(const float4*)(emb + j0);
        float4 c1 = *(const float4*)(emb + j0 + 2);
        xs[p][0] = c0.x; xs[p][1] = c0.z; xs[p][2] = c1.x; xs[p][3] = c1.z;
        ys[p][0] = c0.y; ys[p][1] = c0.w; ys[p][2] = c1.y; ys[p][3] = c1.w;
    }

    // Row-outer, pass-inner: the block's stores sweep its contiguous
    // [i0*S, (i0+8)*S) 128 KB window in ascending address order.
    const float4 z = {0.0f, 0.0f, 0.0f, 0.0f};
#pragma unroll
    for (int rr = 0; rr < PAB_ROWS; ++rr) {
        const int i = i0 + rr;
        if (i >= S) break;
        const float2 pi = pis[rr];
        float* op = out + ((size_t)b * S + i) * S + tid * 4;
#pragma unroll
        for (int p = 0; p < NPASS; ++p) {
            const int jb = p * (PAB_TPB * 4);
            float4 res;
            if (jb > i) {
                res = z;   // whole pass above the diagonal (uniform branch)
            } else {
                res = pab_compute4(pi, xs[p], ys[p], thr, i, jb + tid * 4);
            }
            pab_store_nt(op + (size_t)jb, res);
        }
    }
}

// ---- Fallback (v2 structure) for shapes the primary doesn't cover. -------
#define PAB_ROWS_FB 16
__global__ __launch_bounds__(PAB_TPB) void pab_fused_kernel_fb(
        const float* __restrict__ r, float* __restrict__ out, int S) {
    const int b = blockIdx.z;
    const float2* emb = (const float2*)r + (size_t)b * S;
    const int tid = threadIdx.x;

    const int i0  = blockIdx.y * PAB_ROWS_FB;
    const int jt0 = blockIdx.x * PAB_TPB * 4;
    const int j0  = jt0 + tid * 4;
    size_t orow = ((size_t)b * S + i0) * S + j0;

    if (jt0 > i0 + PAB_ROWS_FB - 1) {   // zero tile (uniform, pre-barrier)
        if (j0 < S) {
            const float4 zz = {0.0f, 0.0f, 0.0f, 0.0f};
#pragma unroll
            for (int rr = 0; rr < PAB_ROWS_FB; ++rr) {
                if (i0 + rr < S) pab_store_nt(out + orow, zz);
                orow += S;
            }
        }
        return;
    }

    const float thr = pab_threshold(emb, S, tid);
    if (j0 >= S) return;   // after all barriers — safe

    float2 pis[PAB_ROWS_FB];
#pragma unroll
    for (int rr = 0; rr < PAB_ROWS_FB; ++rr)
        pis[rr] = emb[min(i0 + rr, S - 1)];

    float4 c0 = *(const float4*)(emb + j0);
    float4 c1 = *(const float4*)(emb + j0 + 2);
    const float xs[4] = {c0.x, c0.z, c1.x, c1.z};
    const float ys[4] = {c0.y, c0.w, c1.y, c1.w};

#pragma unroll
    for (int rr = 0; rr < PAB_ROWS_FB; ++rr) {
        const int i = i0 + rr;
        if (i < S)
            pab_store_nt(out + orow, pab_compute4(pis[rr], xs, ys, thr, i, j0));
        orow += S;
    }
}

extern "C" void kernel_launch(void* const* d_in, const int* in_sizes, int n_in,
                              void* d_out, int out_size, void* d_ws, size_t ws_size,
                              hipStream_t stream) {
    const float* r = (const float*)d_in[0];
    float* out = (float*)d_out;
    (void)d_ws; (void)ws_size;

    // in_sizes[0] = B*S*2, out_size = B*S*S  ->  S = 2*out_size / in_sizes[0]
    long in0 = in_sizes[0];
    int S = (int)((2L * (long)out_size) / in0);
    int B = (int)(in0 / (2L * S));

    dim3 block(PAB_TPB);
    const int tile = PAB_TPB * 4;
    const int npass = (S + tile - 1) / tile;

    if (S % tile == 0 && S % PAB_ROWS == 0 && npass >= 1 && npass <= 4) {
        dim3 grid(S / PAB_ROWS, B);
        switch (npass) {
        case 1: pab_rows_kernel<1><<<grid, block, 0, stream>>>(r, out, S); break;
        case 2: pab_rows_kernel<2><<<grid, block, 0, stream>>>(r, out, S); break;
        case 3: pab_rows_kernel<3><<<grid, block, 0, stream>>>(r, out, S); break;
        default: pab_rows_kernel<4><<<grid, block, 0, stream>>>(r, out, S); break;
        }
    } else {
        dim3 grid((S + tile - 1) / tile,
                  (S + PAB_ROWS_FB - 1) / PAB_ROWS_FB, B);
        pab_fused_kernel_fb<<<grid, block, 0, stream>>>(r, out, S);
    }
}

// Round 4
// 141.686 us; speedup vs baseline: 1.0483x; 1.0483x over previous
//
#include <hip/hip_runtime.h>
#include <math.h>

// ---------------------------------------------------------------------------
// v5 == v2 (best harness-verified: 140.9 us). Revert of v4's NT stores
// (regression) and v3's row-window layout (neutral).
//
// Conclusion carried by R1-R3 evidence: dur_us is dominated by harness-fixed
// reset work (512 MiB poison fill = 81 us + tiny-dispatch reset tail); the
// kernel itself sits at ~its 134 MB write floor (~20 us @ 6.6 TB/s). Four
// structurally independent kernels (compute-halved, tiled, contiguous-window,
// NT) all measured 141 +/- noise.
//
//   * Zero tiles (entirely above the diagonal, ~45% of blocks) skip phase 1
//     and stream zero stores immediately.
//   * Phase 2 specialized: fully-below-diagonal tiles drop the causal
//     compare; branches are block-uniform.
//   * Phase 1 reduction order identical in every block -> bit-identical
//     threshold -> absmax unchanged.
//
//   Phase 1 — per-block redundant batch moments in f64. Closed-form
//   mean/std(ddof=1) of the S*S pairwise dist_sq values:
//     sum_d  = 2N(S2x+S2y) - 2(S1x^2 + S1y^2)
//     sum_d2 = [2N S4x - 8 S3x S1x + 6 S2x^2] + [same for y]
//            + 2*[2N A22 - 4 A21 S1y - 4 A12 S1x + 2 S2x S2y + 4 A11^2]
//
//   forward_bias via 0.5 + 0.5*dx*rsqrt(d2) == 0.5*(1+cos(atan2(dy,dx)));
//   exactly 1.0 at the zero pair, matching atan2(0,1)=0.
// ---------------------------------------------------------------------------
#define PAB_ROWS 16
#define PAB_TPB  256   // threads per block; tile width = PAB_TPB*4 columns

template<bool CAUSAL>
__device__ __forceinline__ void pab_emit_rows(
        const float2* __restrict__ pis, const float* __restrict__ xs,
        const float* __restrict__ ys, float thr, int i0, int j0, int S,
        size_t orow, float* __restrict__ out) {
#pragma unroll
    for (int rr = 0; rr < PAB_ROWS; ++rr) {
        const int i = i0 + rr;
        if (i < S) {
            const float2 pi = pis[rr];
            float4 res;
            float* rp = &res.x;
#pragma unroll
            for (int k = 0; k < 4; ++k) {
                float dx = pi.x - xs[k];
                float dy = pi.y - ys[k];
                float d2 = fmaf(dx, dx, dy * dy);
                float bias = (d2 > 0.0f) ? fmaf(0.5f * dx, rsqrtf(d2), 0.5f)
                                         : 1.0f;
                bool valid = (d2 <= thr);
                if (CAUSAL) valid = valid && ((j0 + k) <= i);
                rp[k] = valid ? bias : 0.0f;
            }
            *(float4*)(out + orow) = res;
        }
        orow += S;
    }
}

__global__ __launch_bounds__(PAB_TPB) void pab_fused_kernel(
        const float* __restrict__ r, float* __restrict__ out, int S) {
    const int b = blockIdx.z;
    const float2* emb = (const float2*)r + (size_t)b * S;
    const int tid = threadIdx.x;

    const int i0  = blockIdx.y * PAB_ROWS;
    const int jt0 = blockIdx.x * PAB_TPB * 4;   // tile's first column
    const int j0  = jt0 + tid * 4;
    size_t orow = ((size_t)b * S + i0) * S + j0;

    // ---- Path A: tile entirely above the diagonal -> zeros only. --------
    // Block-uniform branch BEFORE phase 1 (no barriers crossed): these
    // blocks need no threshold and start saturating the store pipe
    // immediately. Harness poisons d_out, so zeros MUST be written.
    if (jt0 > i0 + PAB_ROWS - 1) {
        if (j0 < S) {
            const float4 z = {0.0f, 0.0f, 0.0f, 0.0f};
#pragma unroll
            for (int rr = 0; rr < PAB_ROWS; ++rr) {
                if (i0 + rr < S) *(float4*)(out + orow) = z;
                orow += S;
            }
        }
        return;
    }

    // ---------------- Phase 1: batch moments (nonzero tiles only) --------
    double s[12];
#pragma unroll
    for (int k = 0; k < 12; ++k) s[k] = 0.0;

    for (int idx0 = tid * 4; idx0 < S; idx0 += PAB_TPB * 4) {
        float4 c0 = *(const float4*)(emb + idx0);      // p0, p1
        float4 c1 = *(const float4*)(emb + idx0 + 2);  // p2, p3
        float xs[4] = {c0.x, c0.z, c1.x, c1.z};
        float ys[4] = {c0.y, c0.w, c1.y, c1.w};
#pragma unroll
        for (int k = 0; k < 4; ++k) {
            if (idx0 + k >= S) break;
            double x = (double)xs[k], y = (double)ys[k];
            double x2 = x * x, y2 = y * y;
            s[0]  += x;        s[1]  += y;
            s[2]  += x2;       s[3]  += y2;
            s[4]  += x2 * x;   s[5]  += y2 * y;
            s[6]  += x2 * x2;  s[7]  += y2 * y2;
            s[8]  += x * y;    s[9]  += x2 * y;
            s[10] += x * y2;   s[11] += x2 * y2;
        }
    }

    // Wave (64-lane) shuffle reduction — no barriers.
#pragma unroll
    for (int off = 32; off > 0; off >>= 1) {
#pragma unroll
        for (int k = 0; k < 12; ++k)
            s[k] += __shfl_down(s[k], off, 64);
    }

    __shared__ double part[PAB_TPB / 64][12];
    __shared__ double tot[12];
    __shared__ float thr_sh;
    const int wave = tid >> 6, lane = tid & 63;
    if (lane == 0) {
#pragma unroll
        for (int k = 0; k < 12; ++k) part[wave][k] = s[k];
    }
    __syncthreads();
    if (tid < 12) {
        double t = 0.0;
#pragma unroll
        for (int w = 0; w < PAB_TPB / 64; ++w) t += part[w][tid];
        tot[tid] = t;
    }
    __syncthreads();
    if (tid == 0) {
        double N = (double)S;
        double M = N * N;
        double S1x = tot[0], S1y = tot[1], S2x = tot[2], S2y = tot[3];
        double S3x = tot[4], S3y = tot[5], S4x = tot[6], S4y = tot[7];
        double A11 = tot[8], A21 = tot[9], A12 = tot[10], A22 = tot[11];

        double sum_d = 2.0 * N * (S2x + S2y) - 2.0 * (S1x * S1x + S1y * S1y);
        double qx = 2.0 * N * S4x - 8.0 * S3x * S1x + 6.0 * S2x * S2x;
        double qy = 2.0 * N * S4y - 8.0 * S3y * S1y + 6.0 * S2y * S2y;
        double cross = 2.0 * N * A22 - 4.0 * A21 * S1y - 4.0 * A12 * S1x
                     + 2.0 * S2x * S2y + 4.0 * A11 * A11;
        double sum_d2 = qx + qy + 2.0 * cross;

        double mean = sum_d / M;
        double var  = (sum_d2 - sum_d * sum_d / M) / (M - 1.0);  // ddof=1
        thr_sh = (float)(mean + 1.25 * sqrt(var));
    }
    __syncthreads();
    const float thr = thr_sh;

    // ---------------- Phase 2: write the 16 x 1024 tile ------------------
    if (j0 >= S) return;   // after all barriers — safe

    // Hoist the 16 block-uniform row points (scalar loads, issued together).
    float2 pis[PAB_ROWS];
#pragma unroll
    for (int rr = 0; rr < PAB_ROWS; ++rr)
        pis[rr] = emb[min(i0 + rr, S - 1)];

    float4 c0 = *(const float4*)(emb + j0);
    float4 c1 = *(const float4*)(emb + j0 + 2);
    const float xs[4] = {c0.x, c0.z, c1.x, c1.z};
    const float ys[4] = {c0.y, c0.w, c1.y, c1.w};

    // Block-uniform specialization: tile fully below the diagonal needs no
    // causal compare (worst row is i0: need jt0 + TILE_W - 1 <= i0).
    if (jt0 + PAB_TPB * 4 - 1 <= i0) {
        pab_emit_rows<false>(pis, xs, ys, thr, i0, j0, S, orow, out);
    } else {
        pab_emit_rows<true>(pis, xs, ys, thr, i0, j0, S, orow, out);
    }
}

extern "C" void kernel_launch(void* const* d_in, const int* in_sizes, int n_in,
                              void* d_out, int out_size, void* d_ws, size_t ws_size,
                              hipStream_t stream) {
    const float* r = (const float*)d_in[0];
    float* out = (float*)d_out;
    (void)d_ws; (void)ws_size;

    // in_sizes[0] = B*S*2, out_size = B*S*S  ->  S = 2*out_size / in_sizes[0]
    long in0 = in_sizes[0];
    int S = (int)((2L * (long)out_size) / in0);
    int B = (int)(in0 / (2L * S));

    dim3 block(PAB_TPB);
    dim3 grid((S + PAB_TPB * 4 - 1) / (PAB_TPB * 4),
              (S + PAB_ROWS - 1) / PAB_ROWS, B);
    pab_fused_kernel<<<grid, block, 0, stream>>>(r, out, S);
}